// Round 1
// baseline (420.403 us; speedup 1.0000x reference)
//
#include <hip/hip_runtime.h>

// QLSTM: SEQ=512, BATCH=512, IN_DIM=128, NQ=8, D=136, 4 gates (f,i,g,o)
// outputs: (SEQ,B,NQ) ++ h_f (B,NQ) ++ c_f (B,NQ), all f32.
//
// Split: z = Wx @ x_t  (big, parallel GEMM -> zx in d_ws)
//      + Wh @ h + b + qp  (tiny, inside sequential scan kernel)

#define SEQ_LEN 512
#define BATCH_N 512
#define IN_DIMC 128
#define NQC 8
#define DTOT 136      // IN_DIM + NQ
#define GQ 32         // 4 gates * 8 qubits
#define M_ROWS (SEQ_LEN * BATCH_N)          // 262144
#define OUT_MAIN (SEQ_LEN * BATCH_N * NQC)  // 2097152

// ---------------------------------------------------------------------------
// Kernel 1: zx[m][gq] = sum_k X[m][k] * W[gq][k]   (m = t*512 + b, k < 128)
// 256 threads/block, 2 rows/thread (strided by 256), W in LDS broadcast.
// ---------------------------------------------------------------------------
__global__ __launch_bounds__(256) void zx_gemm(
    const float* __restrict__ X, const float* __restrict__ W,
    float* __restrict__ ZX)
{
    __shared__ __align__(16) float Wl[IN_DIMC * GQ];   // layout [k][gq]
    const int tid = threadIdx.x;

    #pragma unroll
    for (int i = 0; i < (IN_DIMC * GQ) / 256; ++i) {   // 16 iters
        int idx = i * 256 + tid;
        int k  = idx >> 5;
        int gq = idx & 31;
        Wl[idx] = W[gq * DTOT + k];                    // only x-part (k<128)
    }
    __syncthreads();

    const float4* __restrict__ X4  = (const float4*)X;
    const float4* __restrict__ Wl4 = (const float4*)Wl;

    const int r0 = blockIdx.x * 512 + tid;   // row a
    const int r1 = r0 + 256;                 // row b

    float4 accA[8], accB[8];
    #pragma unroll
    for (int q = 0; q < 8; ++q) {
        accA[q] = make_float4(0.f, 0.f, 0.f, 0.f);
        accB[q] = make_float4(0.f, 0.f, 0.f, 0.f);
    }

#define KSTEP(XA, XB, KIDX)                                                   \
    {                                                                         \
        _Pragma("unroll")                                                     \
        for (int q = 0; q < 8; ++q) {                                         \
            float4 w = Wl4[(KIDX) * 8 + q];                                   \
            accA[q].x = fmaf((XA), w.x, accA[q].x);                           \
            accA[q].y = fmaf((XA), w.y, accA[q].y);                           \
            accA[q].z = fmaf((XA), w.z, accA[q].z);                           \
            accA[q].w = fmaf((XA), w.w, accA[q].w);                           \
            accB[q].x = fmaf((XB), w.x, accB[q].x);                           \
            accB[q].y = fmaf((XB), w.y, accB[q].y);                           \
            accB[q].z = fmaf((XB), w.z, accB[q].z);                           \
            accB[q].w = fmaf((XB), w.w, accB[q].w);                           \
        }                                                                     \
    }

    #pragma unroll 2
    for (int k4 = 0; k4 < 32; ++k4) {
        float4 xa = X4[r0 * 32 + k4];
        float4 xb = X4[r1 * 32 + k4];
        KSTEP(xa.x, xb.x, k4 * 4 + 0)
        KSTEP(xa.y, xb.y, k4 * 4 + 1)
        KSTEP(xa.z, xb.z, k4 * 4 + 2)
        KSTEP(xa.w, xb.w, k4 * 4 + 3)
    }
#undef KSTEP

    float4* __restrict__ Z4 = (float4*)ZX;
    #pragma unroll
    for (int q = 0; q < 8; ++q) {
        Z4[r0 * 8 + q] = accA[q];
        Z4[r1 * 8 + q] = accB[q];
    }
}

// ---------------------------------------------------------------------------
// Kernel 2: sequential scan over t. 32 lanes per batch row: lane = g*8+q.
// 2 rows per wave (64-thread blocks), grid = 256 blocks.
// ---------------------------------------------------------------------------
__device__ __forceinline__ float fast_rcp(float x) {
    return __builtin_amdgcn_rcpf(x);
}
__device__ __forceinline__ float sigmoid_f(float x) {
    return fast_rcp(1.f + __expf(-x));
}
__device__ __forceinline__ float tanh_f(float x) {
    // tanh(x) = 2*sigmoid(2x) - 1 ; no NaN for any finite x
    return fmaf(2.f, fast_rcp(1.f + __expf(-2.f * x)), -1.f);
}

__global__ __launch_bounds__(64) void qlstm_scan(
    const float* __restrict__ ZX, const float* __restrict__ W,
    const float* __restrict__ bv, const float* __restrict__ qp,
    const float* __restrict__ h0, const float* __restrict__ c0,
    float* __restrict__ out)
{
    const int tid = threadIdx.x;
    const int l32 = tid & 31;        // lane within 32-group
    const int hw  = tid >> 5;        // which row of the pair
    const int qi  = l32 & 7;         // qubit index
    const int gq  = l32;             // gate*8 + qubit
    const int row = blockIdx.x * 2 + hw;

    // recurrent weights Wh[gq][j] = W[gq*136 + 128 + j]
    float wh[8];
    #pragma unroll
    for (int j = 0; j < 8; ++j) wh[j] = W[gq * DTOT + IN_DIMC + j];
    const float bias = bv[gq] + qp[gq];

    // every lane keeps a full copy of h (8 values)
    float hreg[8];
    #pragma unroll
    for (int j = 0; j < 8; ++j) hreg[j] = h0[row * 8 + j];
    float c = c0[row * 8 + qi];

    float zcur = ZX[(long)row * 32 + l32];   // t = 0

    float h2 = 0.f;
    for (int t = 0; t < SEQ_LEN; ++t) {
        // prefetch next timestep's zx (independent of recurrence)
        const int tn = (t + 1 < SEQ_LEN) ? (t + 1) : (SEQ_LEN - 1);
        const float znext = ZX[((long)tn * BATCH_N + row) * 32 + l32];

        // z = zx + Wh*h + b + qp
        float z = zcur + bias;
        #pragma unroll
        for (int j = 0; j < 8; ++j) z = fmaf(hreg[j], wh[j], z);

        // qlayer: cumprod(cos(z)) along q within each gate's 8-lane group
        float p = __cosf(z);
        #pragma unroll
        for (int off = 1; off <= 4; off <<= 1) {
            int src = (qi >= off) ? (l32 - off) : l32;
            float pv = __shfl(p, src, 32);
            p = (qi >= off) ? p * pv : p;
        }

        // gather the four gate pre-activations for my qubit
        float p0 = __shfl(p, qi,      32);   // forget
        float p1 = __shfl(p, qi + 8,  32);   // input
        float p2 = __shfl(p, qi + 16, 32);   // update
        float p3 = __shfl(p, qi + 24, 32);   // output

        float fg = sigmoid_f(p0);
        float ig = sigmoid_f(p1);
        float gg = tanh_f(p2);
        float og = sigmoid_f(p3);

        float c2 = fmaf(fg, c, ig * gg);
        h2 = og * tanh_f(c2);
        c = c2;

        // broadcast new h to all lanes (lane j of each 32-group holds h[j&7])
        #pragma unroll
        for (int j = 0; j < 8; ++j) hreg[j] = __shfl(h2, j, 32);

        if (l32 < 8)
            out[((long)t * BATCH_N + row) * 8 + qi] = h2;

        zcur = znext;
    }

    if (l32 < 8) {
        out[OUT_MAIN + row * 8 + qi] = h2;                    // h_f
        out[OUT_MAIN + BATCH_N * NQC + row * 8 + qi] = c;     // c_f
    }
}

// ---------------------------------------------------------------------------
extern "C" void kernel_launch(void* const* d_in, const int* in_sizes, int n_in,
                              void* d_out, int out_size, void* d_ws, size_t ws_size,
                              hipStream_t stream)
{
    const float* X  = (const float*)d_in[0];   // (512,512,128)
    const float* h0 = (const float*)d_in[1];   // (512,8)
    const float* c0 = (const float*)d_in[2];   // (512,8)
    const float* W  = (const float*)d_in[3];   // (4,8,136)
    const float* bv = (const float*)d_in[4];   // (4,8)
    const float* qp = (const float*)d_in[5];   // (4,8)
    float* out = (float*)d_out;
    float* ZX  = (float*)d_ws;                 // 262144*32 f32 = 32 MiB

    zx_gemm<<<M_ROWS / 512, 256, 0, stream>>>(X, W, ZX);
    qlstm_scan<<<BATCH_N / 2, 64, 0, stream>>>(ZX, W, bv, qp, h0, c0, out);
}

// Round 4
// 389.577 us; speedup vs baseline: 1.0791x; 1.0791x over previous
//
#include <hip/hip_runtime.h>

// QLSTM: SEQ=512, BATCH=512, IN_DIM=128, NQ=8, D=136, gates (f,i,g,o)
// out = (512,512,8) ++ h_f(512,8) ++ c_f(512,8), f32.
// K1: ZX[m][gq] = X[m][:128] . W[gq][:128] + b[gq] + qp[gq]   (parallel)
// K2: sequential scan; cross-lane ONLY via __builtin_amdgcn_update_dpp
//     (row_shr/row_shl/row_ror), all direction-calibrated or symmetric.

#define SEQ_LEN 512
#define BATCH_N 512
#define IN_DIMC 128
#define DTOT 136
#define OUT_MAIN (SEQ_LEN * BATCH_N * 8)

// ---------------------------------------------------------------------------
// Kernel 1: 256 thr/block, 2 rows/thread, W staged [k][gq] in LDS (broadcast).
// unroll 1 on k-loop prevents load-hoist VGPR spill. Bias folded in epilogue.
// ---------------------------------------------------------------------------
__global__ __launch_bounds__(256) void zx_gemm(
    const float* __restrict__ X, const float* __restrict__ W,
    const float* __restrict__ bv, const float* __restrict__ qp,
    float* __restrict__ ZX)
{
    __shared__ __align__(16) float Wl[IN_DIMC * 32];   // [k][gq]
    const int tid = threadIdx.x;
    #pragma unroll
    for (int i = 0; i < 16; ++i) {
        int idx = i * 256 + tid;
        Wl[idx] = W[(idx & 31) * DTOT + (idx >> 5)];
    }
    __syncthreads();

    const long r0 = (long)blockIdx.x * 512 + tid;
    const long r1 = r0 + 256;
    const float4* __restrict__ X40 = (const float4*)X + r0 * 32;
    const float4* __restrict__ X41 = (const float4*)X + r1 * 32;
    const float4* __restrict__ W4  = (const float4*)Wl;

    float4 a0[8], a1[8];
    #pragma unroll
    for (int qq = 0; qq < 8; ++qq) {
        a0[qq] = make_float4(0.f, 0.f, 0.f, 0.f);
        a1[qq] = make_float4(0.f, 0.f, 0.f, 0.f);
    }

    float4 xa = X40[0], xb = X41[0];
    #pragma unroll 1
    for (int k4 = 0; k4 < 32; ++k4) {
        float4 xan = xa, xbn = xb;
        if (k4 < 31) { xan = X40[k4 + 1]; xbn = X41[k4 + 1]; }
        #pragma unroll
        for (int c = 0; c < 4; ++c) {
            const float va = (c==0)?xa.x:(c==1)?xa.y:(c==2)?xa.z:xa.w;
            const float vb = (c==0)?xb.x:(c==1)?xb.y:(c==2)?xb.z:xb.w;
            #pragma unroll
            for (int qq = 0; qq < 8; ++qq) {
                const float4 w = W4[(k4 * 4 + c) * 8 + qq];
                a0[qq].x = fmaf(va, w.x, a0[qq].x);
                a0[qq].y = fmaf(va, w.y, a0[qq].y);
                a0[qq].z = fmaf(va, w.z, a0[qq].z);
                a0[qq].w = fmaf(va, w.w, a0[qq].w);
                a1[qq].x = fmaf(vb, w.x, a1[qq].x);
                a1[qq].y = fmaf(vb, w.y, a1[qq].y);
                a1[qq].z = fmaf(vb, w.z, a1[qq].z);
                a1[qq].w = fmaf(vb, w.w, a1[qq].w);
            }
        }
        xa = xan; xb = xbn;
    }

    float4* __restrict__ Z4 = (float4*)ZX;
    #pragma unroll
    for (int qq = 0; qq < 8; ++qq) {
        const int g0 = qq * 4;
        float4 o0 = a0[qq], o1 = a1[qq];
        const float b0 = bv[g0+0] + qp[g0+0];
        const float b1_ = bv[g0+1] + qp[g0+1];
        const float b2 = bv[g0+2] + qp[g0+2];
        const float b3 = bv[g0+3] + qp[g0+3];
        o0.x += b0; o0.y += b1_; o0.z += b2; o0.w += b3;
        o1.x += b0; o1.y += b1_; o1.z += b2; o1.w += b3;
        Z4[r0 * 8 + qq] = o0;
        Z4[r1 * 8 + qq] = o1;
    }
}

// ---------------------------------------------------------------------------
// Kernel 2: 16 lanes per batch row (4 rows/wave). Lane l16 = l&15, q = l&7.
// half hB = l16>>3: hB=0 owns gates {0:f, 2:g~(tanh)}, hB=1 owns {1:i, 3:o}.
// gq0 = l16 (gates 0/1), gq1 = 16+l16 (gates 2/3).
// Cross-lane: DPP only. h-broadcast jmap-calibrated; cumprod dual-direction
// with lane-id probe; partner exchange row_ror:8 (self-inverse).
// ---------------------------------------------------------------------------
#define DPP_F(x, ctrl) \
    __builtin_bit_cast(float, __builtin_amdgcn_update_dpp( \
        0, __builtin_bit_cast(int, (x)), (ctrl), 0xF, 0xF, true))

__global__ __launch_bounds__(64) void qlstm_scan(
    const float* __restrict__ ZX, const float* __restrict__ W,
    const float* __restrict__ h0, const float* __restrict__ c0,
    float* __restrict__ out)
{
    const int l   = threadIdx.x;       // 0..63
    const int l16 = l & 15;
    const int q   = l & 7;
    const int hB  = l16 >> 3;          // which gate-pair half
    const int row = blockIdx.x * 4 + (l >> 4);
    const int gq0 = l16;               // gate hB   (f or i), qubit q
    const int gq1 = 16 + l16;          // gate 2+hB (g~ or o), qubit q

    // --- calibrate row_ror index map: jmap[r] = q-index received under ror r
    const float qf = (float)q;
    int jmap[8];
    jmap[0] = q;
    jmap[1] = (int)DPP_F(qf, 0x121);
    jmap[2] = (int)DPP_F(qf, 0x122);
    jmap[3] = (int)DPP_F(qf, 0x123);
    jmap[4] = (int)DPP_F(qf, 0x124);
    jmap[5] = (int)DPP_F(qf, 0x125);
    jmap[6] = (int)DPP_F(qf, 0x126);
    jmap[7] = (int)DPP_F(qf, 0x127);

    // --- calibrate row_shr direction (per-lane; q=0 lanes never use it)
    const bool dirshr = ((int)DPP_F(qf, 0x111) == q - 1);

    float wh0[8], wh1[8], hror[8];
    #pragma unroll
    for (int r = 0; r < 8; ++r) {
        wh0[r]  = W[gq0 * DTOT + IN_DIMC + jmap[r]];
        wh1[r]  = W[gq1 * DTOT + IN_DIMC + jmap[r]];
        hror[r] = h0[row * 8 + jmap[r]];
    }
    float c = c0[row * 8 + q];

    const bool ge1 = (q >= 1), ge2 = (q >= 2), ge4 = (q >= 4);
    const bool isT = (hB == 0);            // own act1 is tanh for half 0
    const float m1 = isT ? -2.f : -1.f;
    const float A1 = isT ?  2.f :  1.f;
    const float B1 = isT ? -1.f :  0.f;

    // 2-deep ZX prefetch (bias already folded in)
    float zb0  = ZX[(long)row * 32 + l16];
    float zb1  = ZX[(long)row * 32 + 16 + l16];
    float zn10 = ZX[((long)BATCH_N + row) * 32 + l16];
    float zn11 = ZX[((long)BATCH_N + row) * 32 + 16 + l16];

    float hlast = 0.f;
    for (int t = 0; t < SEQ_LEN; ++t) {
        const long tp = (t + 2 < SEQ_LEN) ? (t + 2) : (SEQ_LEN - 1);
        const float zn20 = ZX[(tp * BATCH_N + row) * 32 + l16];
        const float zn21 = ZX[(tp * BATCH_N + row) * 32 + 16 + l16];

        // z = zx+b+qp + Wh.h  (two 4-FMA chains each, summed)
        float s0a = fmaf(hror[0], wh0[0], zb0);
        s0a = fmaf(hror[1], wh0[1], s0a);
        s0a = fmaf(hror[2], wh0[2], s0a);
        s0a = fmaf(hror[3], wh0[3], s0a);
        float s0b = hror[4] * wh0[4];
        s0b = fmaf(hror[5], wh0[5], s0b);
        s0b = fmaf(hror[6], wh0[6], s0b);
        s0b = fmaf(hror[7], wh0[7], s0b);
        const float z0 = s0a + s0b;

        float s1a = fmaf(hror[0], wh1[0], zb1);
        s1a = fmaf(hror[1], wh1[1], s1a);
        s1a = fmaf(hror[2], wh1[2], s1a);
        s1a = fmaf(hror[3], wh1[3], s1a);
        float s1b = hror[4] * wh1[4];
        s1b = fmaf(hror[5], wh1[5], s1b);
        s1b = fmaf(hror[6], wh1[6], s1b);
        s1b = fmaf(hror[7], wh1[7], s1b);
        const float z1 = s1a + s1b;

        float p0 = __cosf(z0), p1 = __cosf(z1);

        // cumprod over q: both directions, select calibrated one
        float ashr = p0, ashl = p0, bshr = p1, bshl = p1;
        { float v = DPP_F(ashr, 0x111); ashr *= ge1 ? v : 1.f; }
        { float v = DPP_F(bshr, 0x111); bshr *= ge1 ? v : 1.f; }
        { float v = DPP_F(ashl, 0x101); ashl *= ge1 ? v : 1.f; }
        { float v = DPP_F(bshl, 0x101); bshl *= ge1 ? v : 1.f; }
        { float v = DPP_F(ashr, 0x112); ashr *= ge2 ? v : 1.f; }
        { float v = DPP_F(bshr, 0x112); bshr *= ge2 ? v : 1.f; }
        { float v = DPP_F(ashl, 0x102); ashl *= ge2 ? v : 1.f; }
        { float v = DPP_F(bshl, 0x102); bshl *= ge2 ? v : 1.f; }
        { float v = DPP_F(ashr, 0x114); ashr *= ge4 ? v : 1.f; }
        { float v = DPP_F(bshr, 0x114); bshr *= ge4 ? v : 1.f; }
        { float v = DPP_F(ashl, 0x104); ashl *= ge4 ? v : 1.f; }
        { float v = DPP_F(bshl, 0x104); bshl *= ge4 ? v : 1.f; }
        p0 = dirshr ? ashr : ashl;
        p1 = dirshr ? bshr : bshl;

        // own activations: act0 = sigmoid (gates f/i); act1 = tanh|sigmoid
        const float act0 = __builtin_amdgcn_rcpf(1.f + __expf(-p0));
        const float act1 = fmaf(
            __builtin_amdgcn_rcpf(1.f + __expf(p1 * m1)), A1, B1);

        // partner (l^8) exchange: row_ror:8 is self-inverse
        const float oth0 = DPP_F(act0, 0x128);
        const float oth1 = DPP_F(act1, 0x128);

        const float f_ = hB ? oth0 : act0;
        const float i_ = hB ? act0 : oth0;
        const float g_ = hB ? oth1 : act1;
        const float o_ = hB ? act1 : oth1;

        const float c2 = fmaf(f_, c, i_ * g_);
        const float th = fmaf(
            __builtin_amdgcn_rcpf(1.f + __expf(-2.f * c2)), 2.f, -1.f);
        const float h2 = o_ * th;
        c = c2;
        hlast = h2;

        if (l16 < 8) out[((long)t * BATCH_N + row) * 8 + q] = h2;

        // h-broadcast for next step (matches jmap-calibrated weights)
        hror[0] = h2;
        hror[1] = DPP_F(h2, 0x121);
        hror[2] = DPP_F(h2, 0x122);
        hror[3] = DPP_F(h2, 0x123);
        hror[4] = DPP_F(h2, 0x124);
        hror[5] = DPP_F(h2, 0x125);
        hror[6] = DPP_F(h2, 0x126);
        hror[7] = DPP_F(h2, 0x127);

        zb0 = zn10; zb1 = zn11;
        zn10 = zn20; zn11 = zn21;
    }

    if (l16 < 8) {
        out[OUT_MAIN + row * 8 + q] = hlast;                  // h_f
        out[OUT_MAIN + BATCH_N * 8 + row * 8 + q] = c;        // c_f
    }
}

// ---------------------------------------------------------------------------
extern "C" void kernel_launch(void* const* d_in, const int* in_sizes, int n_in,
                              void* d_out, int out_size, void* d_ws, size_t ws_size,
                              hipStream_t stream)
{
    const float* X  = (const float*)d_in[0];
    const float* h0 = (const float*)d_in[1];
    const float* c0 = (const float*)d_in[2];
    const float* W  = (const float*)d_in[3];
    const float* bv = (const float*)d_in[4];
    const float* qp = (const float*)d_in[5];
    float* out = (float*)d_out;
    float* ZX  = (float*)d_ws;   // 262144 * 32 f32 = 32 MiB

    zx_gemm<<<(SEQ_LEN * BATCH_N) / 512, 256, 0, stream>>>(X, W, bv, qp, ZX);
    qlstm_scan<<<BATCH_N / 4, 64, 0, stream>>>(ZX, W, h0, c0, out);
}